// Round 1
// baseline (71.934 us; speedup 1.0000x reference)
//
#include <hip/hip_runtime.h>
#include <math.h>

#define NFACE 512
#define NPIX  (256 * 256)

// Camera constants (input-independent, folded from the reference):
// eye = (2.732, 0, -2.732*cos(pi/2)); R rows: x=(C0,0,1), y=(0,1,0), z=(-1,0,C0)
#define EYEX 2.732f
#define EYEZ (-1.6728675276352845e-16f)
#define C0   (6.123233995736766e-17f)

__global__ __launch_bounds__(256) void render_loss_kernel(
    const float* __restrict__ verts,   // (642,3)
    const int*   __restrict__ faces,   // (512,3)
    const float* __restrict__ tex,     // (512,4,4,4,3)
    const float* __restrict__ ref,     // (3,256,256)
    float* __restrict__ out)           // scalar
{
    __shared__ float sfd[NFACE][16];

    // ---- stage per-face data into LDS (2 faces per thread) ----
    for (int f = threadIdx.x; f < NFACE; f += 256) {
        float vx[3], vyy[3], vz[3];
#pragma unroll
        for (int k = 0; k < 3; ++k) {
            int vi = faces[f * 3 + k];
            float px = verts[vi * 3 + 0];
            float py = verts[vi * 3 + 1];
            float pz = verts[vi * 3 + 2];
            float dx = px - EYEX;
            float dz = pz - EYEZ;
            vx[k]  = C0 * dx + dz;   // row x = (C0, 0, 1)
            vyy[k] = py;             // row y = (0, 1, 0)
            vz[k]  = -dx + C0 * dz;  // row z = (-1, 0, C0)
        }
        float ax = vx[0], ay = vyy[0];
        float bx = vx[1], by = vyy[1];
        float cx = vx[2], cy = vyy[2];
        float denom = (bx - ax) * (cy - ay) - (by - ay) * (cx - ax);
        float s = (denom > 0.f) ? 1.f : ((denom < 0.f) ? -1.f : 0.f);
        bool nondeg = fabsf(denom) > 1e-8f;
        float d = nondeg ? denom : 1.0f;
        sfd[f][0] = ax;  sfd[f][1] = ay;
        sfd[f][2] = bx;  sfd[f][3] = by;
        sfd[f][4] = cx;  sfd[f][5] = cy;
        sfd[f][6] = vz[0]; sfd[f][7] = vz[1]; sfd[f][8] = vz[2];
        sfd[f][9] = 1.0f / d;
        sfd[f][10] = s;
        sfd[f][11] = nondeg ? 1.0f : 0.0f;
        sfd[f][12] = 0.f; sfd[f][13] = 0.f; sfd[f][14] = 0.f; sfd[f][15] = 0.f;
    }
    __syncthreads();

    // ---- per-pixel rasterization ----
    int p = blockIdx.x * 256 + threadIdx.x;   // p = j*256 + i
    int i = p & 255;
    int j = p >> 8;
    float Px = ((i + 0.5f) / 256.0f) * 2.0f - 1.0f;
    float Py = 1.0f - ((j + 0.5f) / 256.0f) * 2.0f;

    int   best = -1;
    float bestDepth = INFINITY;

    for (int f = 0; f < NFACE; ++f) {
        const float* o = &sfd[f][0];
        float ax = o[0], ay = o[1], bx = o[2], by = o[3], cx = o[4], cy = o[5];
        float w0 = (cx - bx) * (Py - by) - (cy - by) * (Px - bx);
        float w1 = (ax - cx) * (Py - cy) - (ay - cy) * (Px - cx);
        float w2 = (bx - ax) * (Py - ay) - (by - ay) * (Px - ax);
        float s  = o[10];
        bool inside = (w0 * s >= 0.f) & (w1 * s >= 0.f) & (w2 * s >= 0.f) & (o[11] != 0.f);
        float invd = o[9];
        float depth = (w0 * invd) * o[6] + (w1 * invd) * o[7] + (w2 * invd) * o[8];
        bool upd = inside && (depth > 0.f) && (depth < bestDepth);
        bestDepth = upd ? depth : bestDepth;
        best      = upd ? f : best;
    }

    float r0 = ref[0 * NPIX + p];
    float r1 = ref[1 * NPIX + p];
    float r2 = ref[2 * NPIX + p];

    float col0 = 0.f, col1 = 0.f, col2 = 0.f;
    if (best >= 0) {
        const float* o = &sfd[best][0];
        float ax = o[0], ay = o[1], bx = o[2], by = o[3], cx = o[4], cy = o[5];
        float invd = o[9];
        float w0 = ((cx - bx) * (Py - by) - (cy - by) * (Px - bx)) * invd;
        float w1 = ((ax - cx) * (Py - cy) - (ay - cy) * (Px - cx)) * invd;
        float w2 = ((bx - ax) * (Py - ay) - (by - ay) * (Px - ax)) * invd;
        int t0 = (int)rintf(w0 * 3.0f); t0 = t0 < 0 ? 0 : (t0 > 3 ? 3 : t0);
        int t1 = (int)rintf(w1 * 3.0f); t1 = t1 < 0 ? 0 : (t1 > 3 ? 3 : t1);
        int t2 = (int)rintf(w2 * 3.0f); t2 = t2 < 0 ? 0 : (t2 > 3 ? 3 : t2);
        const float* tp = tex + ((((best * 4 + t0) * 4 + t1) * 4 + t2) * 3);
        col0 = tanhf(tp[0]);
        col1 = tanhf(tp[1]);
        col2 = tanhf(tp[2]);
    }

    float d0 = col0 - r0, d1 = col1 - r1, d2 = col2 - r2;
    float loss = d0 * d0 + d1 * d1 + d2 * d2;

    // ---- reduce: wave shuffle then cross-wave via LDS, one atomic per block ----
    for (int off = 32; off > 0; off >>= 1)
        loss += __shfl_down(loss, off, 64);
    __shared__ float wsum[4];
    int lane = threadIdx.x & 63;
    int wid  = threadIdx.x >> 6;
    if (lane == 0) wsum[wid] = loss;
    __syncthreads();
    if (threadIdx.x == 0) {
        atomicAdd(out, wsum[0] + wsum[1] + wsum[2] + wsum[3]);
    }
}

extern "C" void kernel_launch(void* const* d_in, const int* in_sizes, int n_in,
                              void* d_out, int out_size, void* d_ws, size_t ws_size,
                              hipStream_t stream) {
    const float* verts = (const float*)d_in[0];
    const float* tex   = (const float*)d_in[1];
    const float* ref   = (const float*)d_in[2];
    const int*   faces = (const int*)d_in[3];
    float* out = (float*)d_out;

    hipMemsetAsync(out, 0, sizeof(float), stream);
    render_loss_kernel<<<NPIX / 256, 256, 0, stream>>>(verts, faces, tex, ref, out);
}

// Round 2
// 66.462 us; speedup vs baseline: 1.0823x; 1.0823x over previous
//
#include <hip/hip_runtime.h>
#include <math.h>

#define NFACE 512
#define NPIX  (256 * 256)

// Camera constants (input-independent, folded from the reference):
// eye = (2.732, 0, ~0); R rows: x=(CC0,0,1), y=(0,1,0), z=(-1,0,CC0)
#define EYEX 2.732f
#define EYEZ (-1.6728675276352845e-16f)
#define CC0  (6.123233995736766e-17f)

// Per-face precomputed data, 16 floats:
// [0..8]  A0,B0,C0, A1,B1,C1, A2,B2,C2   : w_k' = A_k*Py + B_k*Px + C_k  (sign folded)
// [9..11] Z0,Z1,Z2                        : depth = w0'*Z0 + w1'*Z1 + w2'*Z2
// [12]    inva = 1/|denom|                : normalized bary = w_k' * inva
// degenerate faces: all zeros -> w'=0 passes inside but depth=0 fails depth>0
__global__ __launch_bounds__(256) void setup_faces(
    const float* __restrict__ verts,   // (642,3)
    const int*   __restrict__ faces,   // (512,3)
    float* __restrict__ fd)            // (512,16)
{
    int f = blockIdx.x * 256 + threadIdx.x;
    if (f >= NFACE) return;
    float vx[3], vy[3], vz[3];
#pragma unroll
    for (int k = 0; k < 3; ++k) {
        int vi = faces[f * 3 + k];
        float px = verts[vi * 3 + 0];
        float py = verts[vi * 3 + 1];
        float pz = verts[vi * 3 + 2];
        float dx = px - EYEX;
        float dz = pz - EYEZ;
        vx[k] = CC0 * dx + dz;
        vy[k] = py;
        vz[k] = -dx + CC0 * dz;
    }
    float ax = vx[0], ay = vy[0];
    float bx = vx[1], by = vy[1];
    float cx = vx[2], cy = vy[2];
    float denom = (bx - ax) * (cy - ay) - (by - ay) * (cx - ax);
    bool nondeg = fabsf(denom) > 1e-8f;
    float s = (denom >= 0.f) ? 1.f : -1.f;
    float inva = 1.0f / fabsf(denom);

    float o[16];
#pragma unroll
    for (int k = 0; k < 16; ++k) o[k] = 0.f;
    if (nondeg) {
        float e0x = cx - bx, e0y = cy - by;   // w0 edge (around b)
        float e1x = ax - cx, e1y = ay - cy;   // w1 edge (around c)
        float e2x = bx - ax, e2y = by - ay;   // w2 edge (around a)
        o[0] = e0x * s;  o[1] = -e0y * s;  o[2] = (e0y * bx - e0x * by) * s;
        o[3] = e1x * s;  o[4] = -e1y * s;  o[5] = (e1y * cx - e1x * cy) * s;
        o[6] = e2x * s;  o[7] = -e2y * s;  o[8] = (e2y * ax - e2x * ay) * s;
        o[9]  = vz[0] * inva;
        o[10] = vz[1] * inva;
        o[11] = vz[2] * inva;
        o[12] = inva;
    }
#pragma unroll
    for (int k = 0; k < 16; ++k) fd[f * 16 + k] = o[k];
}

// Block = 256 threads = 4 waves. 64 pixels per block; wave w tests faces
// [w*128, (w+1)*128). Cross-wave argmin merge via packed (depth|faceIdx) u64.
__global__ __launch_bounds__(256) void raster_loss(
    const float* __restrict__ fd,      // (512,16) face table
    const float* __restrict__ tex,     // (512,4,4,4,3)
    const float* __restrict__ ref,     // (3,256,256)
    float* __restrict__ out)           // scalar
{
    __shared__ unsigned long long smerge[4][64];

    int lane = threadIdx.x & 63;
    int wid  = __builtin_amdgcn_readfirstlane(threadIdx.x >> 6);

    int p = blockIdx.x * 64 + lane;    // 64 consecutive pixels, same row quarter
    int i = p & 255;
    int j = p >> 8;
    float Px = (i + 0.5f) * (2.0f / 256.0f) - 1.0f;
    float Py = 1.0f - (j + 0.5f) * (2.0f / 256.0f);

    const float* fbase = fd + (size_t)wid * 128 * 16;
    float bestDepth = INFINITY;
    int   bestF = -1;

#pragma unroll 4
    for (int ff = 0; ff < 128; ++ff) {
        const float* o = fbase + ff * 16;
        float w0 = o[0] * Py + o[1] * Px + o[2];
        float w1 = o[3] * Py + o[4] * Px + o[5];
        float w2 = o[6] * Py + o[7] * Px + o[8];
        float depth = w0 * o[9] + w1 * o[10] + w2 * o[11];
        bool vis = (w0 >= 0.f) & (w1 >= 0.f) & (w2 >= 0.f) & (depth > 0.f);
        if (vis & (depth < bestDepth)) {
            bestDepth = depth;
            bestF = ff;
        }
    }

    unsigned long long pack = (bestF < 0) ? ~0ull
        : ((unsigned long long)__float_as_uint(bestDepth) << 32)
          | (unsigned)(wid * 128 + bestF);
    smerge[wid][lane] = pack;
    __syncthreads();

    if (wid == 0) {
        unsigned long long m = smerge[0][lane];
        unsigned long long m1 = smerge[1][lane];
        unsigned long long m2 = smerge[2][lane];
        unsigned long long m3 = smerge[3][lane];
        m = m1 < m ? m1 : m;
        m = m2 < m ? m2 : m;
        m = m3 < m ? m3 : m;

        float col0 = 0.f, col1 = 0.f, col2 = 0.f;
        if (m != ~0ull) {
            int best = (int)(unsigned)(m & 0xffffffffu);
            const float* o = fd + best * 16;
            float inva = o[12];
            float w0 = (o[0] * Py + o[1] * Px + o[2]) * inva;
            float w1 = (o[3] * Py + o[4] * Px + o[5]) * inva;
            float w2 = (o[6] * Py + o[7] * Px + o[8]) * inva;
            int t0 = (int)rintf(w0 * 3.0f); t0 = t0 < 0 ? 0 : (t0 > 3 ? 3 : t0);
            int t1 = (int)rintf(w1 * 3.0f); t1 = t1 < 0 ? 0 : (t1 > 3 ? 3 : t1);
            int t2 = (int)rintf(w2 * 3.0f); t2 = t2 < 0 ? 0 : (t2 > 3 ? 3 : t2);
            const float* tp = tex + ((((best * 4 + t0) * 4 + t1) * 4 + t2) * 3);
            col0 = tanhf(tp[0]);
            col1 = tanhf(tp[1]);
            col2 = tanhf(tp[2]);
        }

        float r0 = ref[0 * NPIX + p];
        float r1 = ref[1 * NPIX + p];
        float r2 = ref[2 * NPIX + p];
        float d0 = col0 - r0, d1 = col1 - r1, d2 = col2 - r2;
        float loss = d0 * d0 + d1 * d1 + d2 * d2;

        for (int off = 32; off > 0; off >>= 1)
            loss += __shfl_down(loss, off, 64);
        if (lane == 0) atomicAdd(out, loss);
    }
}

extern "C" void kernel_launch(void* const* d_in, const int* in_sizes, int n_in,
                              void* d_out, int out_size, void* d_ws, size_t ws_size,
                              hipStream_t stream) {
    const float* verts = (const float*)d_in[0];
    const float* tex   = (const float*)d_in[1];
    const float* ref   = (const float*)d_in[2];
    const int*   faces = (const int*)d_in[3];
    float* out = (float*)d_out;
    float* fd  = (float*)d_ws;   // 512*16*4 = 32 KiB face table

    hipMemsetAsync(out, 0, sizeof(float), stream);
    setup_faces<<<2, 256, 0, stream>>>(verts, faces, fd);
    raster_loss<<<NPIX / 64, 256, 0, stream>>>(fd, tex, ref, out);
}

// Round 4
// 35.718 us; speedup vs baseline: 2.0139x; 1.8607x over previous
//
#include <hip/hip_runtime.h>
#include <math.h>

#define NFACE 512
#define NPIX  (256 * 256)

// Camera constants (input-independent, folded from the reference):
#define EYEX 2.732f
#define EYEZ (-1.6728675276352845e-16f)
#define CC0  (6.123233995736766e-17f)

// Per-face table, 16 floats (12 used), all pre-normalized by 1/denom
// (sign of denom folded into edge coefs):
//   [0..8]  An0,Bn0,Cn0, An1,Bn1,Cn1, An2,Bn2,Cn2 : wn_k = An*Py + Bn*Px + Cn
//           (wn_k == reference w_k/d, i.e. the normalized barycentric)
//   [9..11] DA,DB,DC : depth = DA*Py + DB*Px + DC
// degenerate faces: all zeros -> wn=0 passes >=0, depth=0 fails depth>0.
__global__ __launch_bounds__(256) void setup_faces(
    const float* __restrict__ verts,   // (642,3)
    const int*   __restrict__ faces,   // (512,3)
    float* __restrict__ fd,            // (512,16)
    float* __restrict__ out)           // scalar loss (zeroed here)
{
    int f = blockIdx.x * 256 + threadIdx.x;
    if (f == 0) *out = 0.0f;
    if (f >= NFACE) return;
    float vx[3], vy[3], vz[3];
#pragma unroll
    for (int k = 0; k < 3; ++k) {
        int vi = faces[f * 3 + k];
        float px = verts[vi * 3 + 0];
        float py = verts[vi * 3 + 1];
        float pz = verts[vi * 3 + 2];
        float dx = px - EYEX;
        float dz = pz - EYEZ;
        vx[k] = CC0 * dx + dz;
        vy[k] = py;
        vz[k] = -dx + CC0 * dz;
    }
    float ax = vx[0], ay = vy[0];
    float bx = vx[1], by = vy[1];
    float cx = vx[2], cy = vy[2];
    float denom = (bx - ax) * (cy - ay) - (by - ay) * (cx - ax);
    bool nondeg = fabsf(denom) > 1e-8f;
    float s = (denom >= 0.f) ? 1.f : -1.f;
    float si = s / fabsf(denom);          // == 1/denom

    float o[16];
#pragma unroll
    for (int k = 0; k < 16; ++k) o[k] = 0.f;
    if (nondeg) {
        float e0x = cx - bx, e0y = cy - by;
        float e1x = ax - cx, e1y = ay - cy;
        float e2x = bx - ax, e2y = by - ay;
        o[0] = e0x * si;  o[1] = -e0y * si;  o[2] = (e0y * bx - e0x * by) * si;
        o[3] = e1x * si;  o[4] = -e1y * si;  o[5] = (e1y * cx - e1x * cy) * si;
        o[6] = e2x * si;  o[7] = -e2y * si;  o[8] = (e2y * ax - e2x * ay) * si;
        o[9]  = o[0] * vz[0] + o[3] * vz[1] + o[6] * vz[2];   // DA
        o[10] = o[1] * vz[0] + o[4] * vz[1] + o[7] * vz[2];   // DB
        o[11] = o[2] * vz[0] + o[5] * vz[1] + o[8] * vz[2];   // DC
    }
#pragma unroll
    for (int k = 0; k < 16; ++k) fd[f * 16 + k] = o[k];
}

// Register-resident rasterizer: lane owns 8 faces (face = slot*64+lane),
// wave owns a 16-pixel strip. 1024 blocks x 4 waves = 4096 strips = 65536 px.
__global__ __launch_bounds__(256, 4) void raster_loss(
    const float4* __restrict__ fd4,    // (512,4) float4 rows
    const float* __restrict__ tex,     // (512,4,4,4,3)
    const float* __restrict__ ref,     // (3,256,256)
    float* __restrict__ out)
{
    int lane = threadIdx.x & 63;
    int wid  = threadIdx.x >> 6;
    int unit = blockIdx.x * 4 + wid;     // 0..4095
    int pbase = unit * 16;               // 16 consecutive pixels, same row
    int jrow  = pbase >> 8;
    int ibase = pbase & 255;
    float Py = 1.0f - (jrow + 0.5f) * (2.0f / 256.0f);

    // ---- load my 8 faces' coefficients into registers ----
    float c[8][12];
#pragma unroll
    for (int s = 0; s < 8; ++s) {
        const float4* rp = fd4 + (size_t)(s * 64 + lane) * 4;
        float4 q0 = rp[0], q1 = rp[1], q2 = rp[2];
        c[s][0] = q0.x; c[s][1] = q0.y; c[s][2]  = q0.z; c[s][3]  = q0.w;
        c[s][4] = q1.x; c[s][5] = q1.y; c[s][6]  = q1.z; c[s][7]  = q1.w;
        c[s][8] = q2.x; c[s][9] = q2.y; c[s][10] = q2.z; c[s][11] = q2.w;
    }

    unsigned long long mypack = ~0ull;

#pragma unroll
    for (int b = 0; b < 4; ++b) {
        float bd[4];
        int   bf[4];
#pragma unroll
        for (int q = 0; q < 4; ++q) { bd[q] = INFINITY; bf[q] = 0; }

#pragma unroll
        for (int s = 0; s < 8; ++s) {
#pragma unroll
            for (int q = 0; q < 4; ++q) {
                int t = b * 4 + q;
                float Px = (ibase + t + 0.5f) * (2.0f / 256.0f) - 1.0f;
                float w0 = fmaf(c[s][1], Px, fmaf(c[s][0], Py, c[s][2]));
                float w1 = fmaf(c[s][4], Px, fmaf(c[s][3], Py, c[s][5]));
                float w2 = fmaf(c[s][7], Px, fmaf(c[s][6], Py, c[s][8]));
                float dep = fmaf(c[s][10], Px, fmaf(c[s][9], Py, c[s][11]));
                float mn = fminf(fminf(w0, w1), w2);
                bool upd = (mn >= 0.f) & (dep > 0.f) & (dep < bd[q]);
                bd[q] = upd ? dep : bd[q];
                bf[q] = upd ? (s * 64 + lane) : bf[q];
            }
        }

        unsigned long long pk[4];
#pragma unroll
        for (int q = 0; q < 4; ++q)
            pk[q] = ((unsigned long long)__float_as_uint(bd[q]) << 32)
                    | (unsigned)bf[q];

        // 4 interleaved u64-min butterflies across the wave
#pragma unroll
        for (int st = 1; st < 64; st <<= 1) {
#pragma unroll
            for (int q = 0; q < 4; ++q) {
                unsigned long long o = __shfl_xor(pk[q], st, 64);
                pk[q] = (o < pk[q]) ? o : pk[q];
            }
        }
#pragma unroll
        for (int q = 0; q < 4; ++q) {
            int t = b * 4 + q;
            mypack = (lane == t) ? pk[q] : mypack;
        }
    }

    // ---- epilogue: lanes 0..15 each finish one pixel ----
    float loss = 0.f;
    if (lane < 16) {
        int p = pbase + lane;
        float Px = (ibase + lane + 0.5f) * (2.0f / 256.0f) - 1.0f;
        float col0 = 0.f, col1 = 0.f, col2 = 0.f;
        unsigned hi = (unsigned)(mypack >> 32);
        if (hi != 0x7f800000u) {           // depth != +inf -> hit
            int best = (int)(unsigned)(mypack & 0xffffffffu);
            const float4* rp = fd4 + (size_t)best * 4;
            float4 q0 = rp[0], q1 = rp[1], q2 = rp[2];
            float w0 = fmaf(q0.y, Px, fmaf(q0.x, Py, q0.z));
            float w1 = fmaf(q1.x, Px, fmaf(q0.w, Py, q1.y));
            float w2 = fmaf(q1.w, Px, fmaf(q1.z, Py, q2.x));
            int t0 = (int)rintf(w0 * 3.0f); t0 = t0 < 0 ? 0 : (t0 > 3 ? 3 : t0);
            int t1 = (int)rintf(w1 * 3.0f); t1 = t1 < 0 ? 0 : (t1 > 3 ? 3 : t1);
            int t2 = (int)rintf(w2 * 3.0f); t2 = t2 < 0 ? 0 : (t2 > 3 ? 3 : t2);
            const float* tp = tex + ((((best * 4 + t0) * 4 + t1) * 4 + t2) * 3);
            col0 = tanhf(tp[0]);
            col1 = tanhf(tp[1]);
            col2 = tanhf(tp[2]);
        }
        float r0 = ref[0 * NPIX + p];
        float r1 = ref[1 * NPIX + p];
        float r2 = ref[2 * NPIX + p];
        float d0 = col0 - r0, d1 = col1 - r1, d2 = col2 - r2;
        loss = d0 * d0 + d1 * d1 + d2 * d2;
    }

    // wave reduce, then one atomic per block
    for (int off = 32; off > 0; off >>= 1)
        loss += __shfl_down(loss, off, 64);
    __shared__ float wsum[4];
    if (lane == 0) wsum[wid] = loss;
    __syncthreads();
    if (threadIdx.x == 0)
        atomicAdd(out, wsum[0] + wsum[1] + wsum[2] + wsum[3]);
}

extern "C" void kernel_launch(void* const* d_in, const int* in_sizes, int n_in,
                              void* d_out, int out_size, void* d_ws, size_t ws_size,
                              hipStream_t stream) {
    const float* verts = (const float*)d_in[0];
    const float* tex   = (const float*)d_in[1];
    const float* ref   = (const float*)d_in[2];
    const int*   faces = (const int*)d_in[3];
    float* out = (float*)d_out;
    float* fd  = (float*)d_ws;   // 512*16*4 = 32 KiB face table

    setup_faces<<<2, 256, 0, stream>>>(verts, faces, fd, out);
    // 4096 pixel-strips (16 px each), 4 waves/block -> 1024 blocks.
    raster_loss<<<1024, 256, 0, stream>>>((const float4*)fd, tex, ref, out);
}

// Round 5
// 30.661 us; speedup vs baseline: 2.3461x; 1.1649x over previous
//
#include <hip/hip_runtime.h>
#include <math.h>

#define NFACE 512
#define NPIX  (256 * 256)

// Camera constants (input-independent, folded from the reference):
#define EYEX 2.732f
#define EYEZ (-1.6728675276352845e-16f)
#define CC0  (6.123233995736766e-17f)

// Per-face table, 16 floats (12 used), all pre-normalized by 1/denom
// (sign of denom folded into edge coefs):
//   [0..8]  A0,B0,C0, A1,B1,C1, A2,B2,C2 : wn_k = A_k*Py + B_k*Px + C_k
//           (wn_k == reference w_k/d, the normalized barycentric)
//   [9..11] DA,DB,DC : depth = DA*Py + DB*Px + DC
// degenerate faces: all zeros -> wn=0 passes >=0, depth=0 fails depth>0.
__global__ __launch_bounds__(256) void setup_faces(
    const float* __restrict__ verts,   // (642,3)
    const int*   __restrict__ faces,   // (512,3)
    float* __restrict__ fd,            // (512,16)
    float* __restrict__ out)           // scalar loss (zeroed here)
{
    int f = blockIdx.x * 256 + threadIdx.x;
    if (f == 0) *out = 0.0f;
    if (f >= NFACE) return;
    float vx[3], vy[3], vz[3];
#pragma unroll
    for (int k = 0; k < 3; ++k) {
        int vi = faces[f * 3 + k];
        float px = verts[vi * 3 + 0];
        float py = verts[vi * 3 + 1];
        float pz = verts[vi * 3 + 2];
        float dx = px - EYEX;
        float dz = pz - EYEZ;
        vx[k] = CC0 * dx + dz;
        vy[k] = py;
        vz[k] = -dx + CC0 * dz;
    }
    float ax = vx[0], ay = vy[0];
    float bx = vx[1], by = vy[1];
    float cx = vx[2], cy = vy[2];
    float denom = (bx - ax) * (cy - ay) - (by - ay) * (cx - ax);
    bool nondeg = fabsf(denom) > 1e-8f;
    float s = (denom >= 0.f) ? 1.f : -1.f;
    float si = s / fabsf(denom);          // == 1/denom

    float o[16];
#pragma unroll
    for (int k = 0; k < 16; ++k) o[k] = 0.f;
    if (nondeg) {
        float e0x = cx - bx, e0y = cy - by;
        float e1x = ax - cx, e1y = ay - cy;
        float e2x = bx - ax, e2y = by - ay;
        o[0] = e0x * si;  o[1] = -e0y * si;  o[2] = (e0y * bx - e0x * by) * si;
        o[3] = e1x * si;  o[4] = -e1y * si;  o[5] = (e1y * cx - e1x * cy) * si;
        o[6] = e2x * si;  o[7] = -e2y * si;  o[8] = (e2y * ax - e2x * ay) * si;
        o[9]  = o[0] * vz[0] + o[3] * vz[1] + o[6] * vz[2];   // DA
        o[10] = o[1] * vz[0] + o[4] * vz[1] + o[7] * vz[2];   // DB
        o[11] = o[2] * vz[0] + o[5] * vz[1] + o[8] * vz[2];   // DC
    }
#pragma unroll
    for (int k = 0; k < 16; ++k) fd[f * 16 + k] = o[k];
}

// Register-resident rasterizer: lane owns 8 faces (face = slot*64+lane),
// wave owns a 16-pixel strip. Strip-incremental edge evaluation:
// w(x0 + t*DX) = w(x0) + t*(B*DX). Argmin via 32-bit packed
// (depth_bits & ~511) | face, u32-min butterfly across the wave.
#define DXSTEP (2.0f / 256.0f)

__global__ __launch_bounds__(256, 4) void raster_loss(
    const float4* __restrict__ fd4,    // (512,4) float4 rows
    const float* __restrict__ tex,     // (512,4,4,4,3)
    const float* __restrict__ ref,     // (3,256,256)
    float* __restrict__ out)
{
    int lane = threadIdx.x & 63;
    int wid  = threadIdx.x >> 6;
    int unit = blockIdx.x * 4 + wid;     // 0..4095
    int pbase = unit * 16;               // 16 consecutive pixels, same row
    int jrow  = pbase >> 8;
    int ibase = pbase & 255;
    float Py = 1.0f - (jrow + 0.5f) * DXSTEP;
    float x0 = (ibase + 0.5f) * DXSTEP - 1.0f;

    // ---- prepass: per-slot strip base values + per-pixel deltas ----
    float w0b[8], w1b[8], w2b[8], dpb[8];
    float d0[8], d1[8], d2[8], dd[8];
    unsigned fl[8];
#pragma unroll
    for (int s = 0; s < 8; ++s) {
        const float4* rp = fd4 + (size_t)(s * 64 + lane) * 4;
        float4 q0 = rp[0], q1 = rp[1], q2 = rp[2];
        // A0=q0.x B0=q0.y C0=q0.z | A1=q0.w B1=q1.x C1=q1.y
        // A2=q1.z B2=q1.w C2=q2.x | DA=q2.y DB=q2.z DC=q2.w
        w0b[s] = fmaf(q0.x, Py, fmaf(q0.y, x0, q0.z));
        w1b[s] = fmaf(q0.w, Py, fmaf(q1.x, x0, q1.y));
        w2b[s] = fmaf(q1.z, Py, fmaf(q1.w, x0, q2.x));
        dpb[s] = fmaf(q2.y, Py, fmaf(q2.z, x0, q2.w));
        d0[s] = q0.y * DXSTEP;
        d1[s] = q1.x * DXSTEP;
        d2[s] = q1.w * DXSTEP;
        dd[s] = q2.z * DXSTEP;
        fl[s] = (unsigned)(s * 64 + lane);
    }

    unsigned mypack = 0xFFFFFFFFu;

#pragma unroll
    for (int b = 0; b < 2; ++b) {
        unsigned pk[8];
#pragma unroll
        for (int q = 0; q < 8; ++q) pk[q] = 0xFFFFFFFFu;

#pragma unroll
        for (int s = 0; s < 8; ++s) {
#pragma unroll
            for (int q = 0; q < 8; ++q) {
                float tf = (float)(b * 8 + q);
                float w0  = fmaf(tf, d0[s], w0b[s]);
                float w1  = fmaf(tf, d1[s], w1b[s]);
                float w2  = fmaf(tf, d2[s], w2b[s]);
                float dep = fmaf(tf, dd[s], dpb[s]);
                float mn = fminf(fminf(w0, w1), w2);
                bool vis = (mn >= 0.f) & (dep > 0.f);
                unsigned cand = (__float_as_uint(dep) & 0xFFFFFE00u) | fl[s];
                cand = vis ? cand : 0xFFFFFFFFu;
                pk[q] = pk[q] < cand ? pk[q] : cand;
            }
        }

        // 8 interleaved u32-min butterflies across the wave
#pragma unroll
        for (int st = 1; st < 64; st <<= 1) {
#pragma unroll
            for (int q = 0; q < 8; ++q) {
                unsigned o = (unsigned)__shfl_xor((int)pk[q], st, 64);
                pk[q] = pk[q] < o ? pk[q] : o;
            }
        }
#pragma unroll
        for (int q = 0; q < 8; ++q) {
            int t = b * 8 + q;
            mypack = (lane == t) ? pk[q] : mypack;
        }
    }

    // ---- epilogue: lanes 0..15 each finish one pixel ----
    float loss = 0.f;
    if (lane < 16) {
        int p = pbase + lane;
        float Px = fmaf((float)lane, DXSTEP, x0);
        float col0 = 0.f, col1 = 0.f, col2 = 0.f;
        if (mypack != 0xFFFFFFFFu) {       // hit
            int best = (int)(mypack & 511u);
            const float4* rp = fd4 + (size_t)best * 4;
            float4 q0 = rp[0], q1 = rp[1], q2 = rp[2];
            float w0 = fmaf(q0.y, Px, fmaf(q0.x, Py, q0.z));
            float w1 = fmaf(q1.x, Px, fmaf(q0.w, Py, q1.y));
            float w2 = fmaf(q1.w, Px, fmaf(q1.z, Py, q2.x));
            int t0 = (int)rintf(w0 * 3.0f); t0 = t0 < 0 ? 0 : (t0 > 3 ? 3 : t0);
            int t1 = (int)rintf(w1 * 3.0f); t1 = t1 < 0 ? 0 : (t1 > 3 ? 3 : t1);
            int t2 = (int)rintf(w2 * 3.0f); t2 = t2 < 0 ? 0 : (t2 > 3 ? 3 : t2);
            const float* tp = tex + ((((best * 4 + t0) * 4 + t1) * 4 + t2) * 3);
            col0 = tanhf(tp[0]);
            col1 = tanhf(tp[1]);
            col2 = tanhf(tp[2]);
        }
        float r0 = ref[0 * NPIX + p];
        float r1 = ref[1 * NPIX + p];
        float r2 = ref[2 * NPIX + p];
        float e0 = col0 - r0, e1 = col1 - r1, e2 = col2 - r2;
        loss = e0 * e0 + e1 * e1 + e2 * e2;
    }

    // wave reduce, then one atomic per block
    for (int off = 32; off > 0; off >>= 1)
        loss += __shfl_down(loss, off, 64);
    __shared__ float wsum[4];
    if (lane == 0) wsum[wid] = loss;
    __syncthreads();
    if (threadIdx.x == 0)
        atomicAdd(out, wsum[0] + wsum[1] + wsum[2] + wsum[3]);
}

extern "C" void kernel_launch(void* const* d_in, const int* in_sizes, int n_in,
                              void* d_out, int out_size, void* d_ws, size_t ws_size,
                              hipStream_t stream) {
    const float* verts = (const float*)d_in[0];
    const float* tex   = (const float*)d_in[1];
    const float* ref   = (const float*)d_in[2];
    const int*   faces = (const int*)d_in[3];
    float* out = (float*)d_out;
    float* fd  = (float*)d_ws;   // 512*16*4 = 32 KiB face table

    setup_faces<<<2, 256, 0, stream>>>(verts, faces, fd, out);
    // 4096 pixel-strips (16 px each), 4 waves/block -> 1024 blocks.
    raster_loss<<<1024, 256, 0, stream>>>((const float4*)fd, tex, ref, out);
}

// Round 6
// 30.484 us; speedup vs baseline: 2.3597x; 1.0058x over previous
//
#include <hip/hip_runtime.h>
#include <math.h>

#define NFACE 512
#define NPIX  (256 * 256)
#define DXS   (2.0f / 256.0f)

// Camera constants (input-independent, folded from the reference):
#define EYEX 2.732f
#define EYEZ (-1.6728675276352845e-16f)
#define CC0  (6.123233995736766e-17f)

// Per-face record, 16 floats, coefs pre-normalized by 1/denom (sign folded):
//   [0..8]  A0,B0,C0, A1,B1,C1, A2,B2,C2 : wn_k = A_k*Py + B_k*Px + C_k
//   [9..11] DA,DB,DC : depth = DA*Py + DB*Px + DC   (depth>0 whenever inside,
//           since camera-space z in [1.73,3.73] for all verts)
//   [12..15] xmin,xmax,ymin,ymax screen bbox (+margin)
// Degenerate faces & the dummy face NFACE: C0=-1 (never inside), empty bbox.
__global__ __launch_bounds__(256) void setup_faces(
    const float* __restrict__ verts,   // (642,3)
    const int*   __restrict__ faces,   // (512,3)
    float* __restrict__ fd,            // (513,16)
    float* __restrict__ out)           // scalar loss (zeroed here)
{
    int f = blockIdx.x * 256 + threadIdx.x;
    if (f == 0) *out = 0.0f;
    if (f > NFACE) return;

    float o[16];
#pragma unroll
    for (int k = 0; k < 16; ++k) o[k] = 0.f;
    o[2]  = -1.0f;                  // never inside
    o[12] = 2e30f;  o[13] = -2e30f; // empty bbox
    o[14] = 2e30f;  o[15] = -2e30f;

    if (f < NFACE) {
        float vx[3], vy[3], vz[3];
#pragma unroll
        for (int k = 0; k < 3; ++k) {
            int vi = faces[f * 3 + k];
            float px = verts[vi * 3 + 0];
            float py = verts[vi * 3 + 1];
            float pz = verts[vi * 3 + 2];
            float dx = px - EYEX;
            float dz = pz - EYEZ;
            vx[k] = CC0 * dx + dz;
            vy[k] = py;
            vz[k] = -dx + CC0 * dz;
        }
        float ax = vx[0], ay = vy[0];
        float bx = vx[1], by = vy[1];
        float cx = vx[2], cy = vy[2];
        float denom = (bx - ax) * (cy - ay) - (by - ay) * (cx - ax);
        if (fabsf(denom) > 1e-8f) {
            float s  = (denom >= 0.f) ? 1.f : -1.f;
            float si = s / fabsf(denom);          // == 1/denom
            float e0x = cx - bx, e0y = cy - by;
            float e1x = ax - cx, e1y = ay - cy;
            float e2x = bx - ax, e2y = by - ay;
            o[0] = e0x * si;  o[1] = -e0y * si;  o[2] = (e0y * bx - e0x * by) * si;
            o[3] = e1x * si;  o[4] = -e1y * si;  o[5] = (e1y * cx - e1x * cy) * si;
            o[6] = e2x * si;  o[7] = -e2y * si;  o[8] = (e2y * ax - e2x * ay) * si;
            o[9]  = o[0] * vz[0] + o[3] * vz[1] + o[6] * vz[2];   // DA
            o[10] = o[1] * vz[0] + o[4] * vz[1] + o[7] * vz[2];   // DB
            o[11] = o[2] * vz[0] + o[5] * vz[1] + o[8] * vz[2];   // DC
            float xmn = fminf(fminf(ax, bx), cx);
            float xmx = fmaxf(fmaxf(ax, bx), cx);
            float ymn = fminf(fminf(ay, by), cy);
            float ymx = fmaxf(fmaxf(ay, by), cy);
            o[12] = xmn - 1e-4f;  o[13] = xmx + 1e-4f;
            o[14] = ymn - 1e-4f;  o[15] = ymx + 1e-4f;
        }
    }
#pragma unroll
    for (int k = 0; k < 16; ++k) fd[f * 16 + k] = o[k];
}

// Wave = one 16-px strip. Per wave: ballot-compacted LDS list of faces whose
// bbox hits (row, strip-x-range), then list-driven raster (1 face/lane/iter,
// 16 px inner, pack (depth_bits&~511)|face, u32-min butterfly at the end).
__global__ __launch_bounds__(256, 4) void raster_loss(
    const float4* __restrict__ fd4,    // (513,4) float4 rows
    const float* __restrict__ tex,     // (512,4,4,4,3)
    const float* __restrict__ ref,     // (3,256,256)
    float* __restrict__ out)
{
    __shared__ unsigned short lists[4][512];
    __shared__ float wsum[4];

    int lane = threadIdx.x & 63;
    int wid  = threadIdx.x >> 6;
    // spread a block's 4 waves across rows 64 apart for load balance
    int strip = wid * 1024 + blockIdx.x;   // 0..4095
    int pbase = strip * 16;
    int row   = pbase >> 8;
    int ib    = pbase & 255;
    float Py = 1.0f - (row + 0.5f) * DXS;
    float x0 = (ib + 0.5f) * DXS - 1.0f;
    float x1 = x0 + 15.0f * DXS;

    // ---- bbox cull -> compacted per-wave list ----
    unsigned short* mylist = lists[wid];
    int cnt = 0;
#pragma unroll
    for (int r = 0; r < 8; ++r) {
        int f = r * 64 + lane;
        float4 bb = fd4[f * 4 + 3];   // xmin,xmax,ymin,ymax
        bool pred = (bb.x <= x1) & (bb.y >= x0) & (bb.z <= Py) & (bb.w >= Py);
        unsigned long long m = __ballot(pred);
        if (pred) {
            int ofs = cnt + (int)__popcll(m & ((1ull << lane) - 1ull));
            mylist[ofs] = (unsigned short)f;
        }
        cnt += (int)__popcll(m);
    }

    // ---- list-driven raster ----
    unsigned pk[16];
#pragma unroll
    for (int q = 0; q < 16; ++q) pk[q] = 0xFFFFFFFFu;

    int nit = (cnt + 63) >> 6;
    for (int it = 0; it < nit; ++it) {
        int si = it * 64 + lane;
        int fi = (si < cnt) ? (int)mylist[si] : NFACE;   // dummy never wins
        const float4* rp = fd4 + (size_t)fi * 4;
        float4 q0 = rp[0], q1 = rp[1], q2 = rp[2];
        // strip-incremental: value at x0 + per-pixel delta
        float w0b = fmaf(q0.x, Py, fmaf(q0.y, x0, q0.z));
        float w1b = fmaf(q0.w, Py, fmaf(q1.x, x0, q1.y));
        float w2b = fmaf(q1.z, Py, fmaf(q1.w, x0, q2.x));
        float dpb = fmaf(q2.y, Py, fmaf(q2.z, x0, q2.w));
        float d0 = q0.y * DXS, d1 = q1.x * DXS, d2 = q1.w * DXS, dd = q2.z * DXS;
        unsigned idb = (unsigned)fi;
#pragma unroll
        for (int q = 0; q < 16; ++q) {
            float tf = (float)q;
            float w0  = fmaf(tf, d0, w0b);
            float w1  = fmaf(tf, d1, w1b);
            float w2  = fmaf(tf, d2, w2b);
            float dep = fmaf(tf, dd, dpb);
            float mn  = fminf(fminf(w0, w1), w2);
            unsigned cand = (__float_as_uint(dep) & 0xFFFFFE00u) | idb;
            cand = (mn >= 0.f) ? cand : 0xFFFFFFFFu;
            pk[q] = pk[q] < cand ? pk[q] : cand;
        }
    }

    // ---- 16 interleaved u32-min butterflies across the wave ----
#pragma unroll
    for (int st = 1; st < 64; st <<= 1) {
#pragma unroll
        for (int q = 0; q < 16; ++q) {
            unsigned o = (unsigned)__shfl_xor((int)pk[q], st, 64);
            pk[q] = pk[q] < o ? pk[q] : o;
        }
    }
    unsigned mypack = 0xFFFFFFFFu;
#pragma unroll
    for (int q = 0; q < 16; ++q)
        mypack = (lane == q) ? pk[q] : mypack;

    // ---- epilogue: lanes 0..15 each finish one pixel ----
    float loss = 0.f;
    if (lane < 16) {
        int p = pbase + lane;
        float Px = fmaf((float)lane, DXS, x0);
        float col0 = 0.f, col1 = 0.f, col2 = 0.f;
        if (mypack != 0xFFFFFFFFu) {       // hit
            int best = (int)(mypack & 511u);
            const float4* rp = fd4 + (size_t)best * 4;
            float4 q0 = rp[0], q1 = rp[1], q2 = rp[2];
            float w0 = fmaf(q0.y, Px, fmaf(q0.x, Py, q0.z));
            float w1 = fmaf(q1.x, Px, fmaf(q0.w, Py, q1.y));
            float w2 = fmaf(q1.w, Px, fmaf(q1.z, Py, q2.x));
            int t0 = (int)rintf(w0 * 3.0f); t0 = t0 < 0 ? 0 : (t0 > 3 ? 3 : t0);
            int t1 = (int)rintf(w1 * 3.0f); t1 = t1 < 0 ? 0 : (t1 > 3 ? 3 : t1);
            int t2 = (int)rintf(w2 * 3.0f); t2 = t2 < 0 ? 0 : (t2 > 3 ? 3 : t2);
            const float* tp = tex + ((((best * 4 + t0) * 4 + t1) * 4 + t2) * 3);
            col0 = tanhf(tp[0]);
            col1 = tanhf(tp[1]);
            col2 = tanhf(tp[2]);
        }
        float r0 = ref[0 * NPIX + p];
        float r1 = ref[1 * NPIX + p];
        float r2 = ref[2 * NPIX + p];
        float e0 = col0 - r0, e1 = col1 - r1, e2 = col2 - r2;
        loss = e0 * e0 + e1 * e1 + e2 * e2;
    }

    // wave reduce, then one atomic per block
    for (int off = 32; off > 0; off >>= 1)
        loss += __shfl_down(loss, off, 64);
    if (lane == 0) wsum[wid] = loss;
    __syncthreads();
    if (threadIdx.x == 0)
        atomicAdd(out, wsum[0] + wsum[1] + wsum[2] + wsum[3]);
}

extern "C" void kernel_launch(void* const* d_in, const int* in_sizes, int n_in,
                              void* d_out, int out_size, void* d_ws, size_t ws_size,
                              hipStream_t stream) {
    const float* verts = (const float*)d_in[0];
    const float* tex   = (const float*)d_in[1];
    const float* ref   = (const float*)d_in[2];
    const int*   faces = (const int*)d_in[3];
    float* out = (float*)d_out;
    float* fd  = (float*)d_ws;   // 513*16*4 = 32.8 KiB face table (incl. dummy)

    setup_faces<<<3, 256, 0, stream>>>(verts, faces, fd, out);
    raster_loss<<<1024, 256, 0, stream>>>((const float4*)fd, tex, ref, out);
}